// Round 11
// baseline (63.031 us; speedup 1.0000x reference)
//
#include <hip/hip_runtime.h>
#include <hip/hip_bf16.h>

#define N_NODES 131072
#define BATCH 128
#define H 256
#define TPB 4                 // tiles per block
#define GRID 512              // 512 blocks * 4 tiles * 64 rows = 131072 nodes

typedef _Float16 half8 __attribute__((ext_vector_type(8)));
typedef _Float16 half4 __attribute__((ext_vector_type(4)));
typedef float floatx4 __attribute__((ext_vector_type(4)));

// ---------------------------------------------------------------------------
// Prep: blocks 0..31 pack W1 into MFMA fragment order (f16); blocks 32..159
// zero pacc (128*256); block 32 also zeros pz (128). Runs every call so the
// atomic accumulators start from zero on each graph replay.
// ---------------------------------------------------------------------------
__global__ __launch_bounds__(256) void prep_kernel(
    const float* __restrict__ W1, _Float16* __restrict__ W1p,
    float* __restrict__ pacc, float* __restrict__ pz)
{
    const int bid = blockIdx.x;
    const int tid = threadIdx.x;
    if (bid < 32) {
        const int g = bid * 256 + tid;          // [0, 8192)
        const int ct = g >> 9;
        const int ks = (g >> 6) & 7;
        const int l  = g & 63;
        const int k0 = ks * 32 + (l >> 4) * 8;
        const int col = ct * 16 + (l & 15);
        half8 h;
        #pragma unroll
        for (int j = 0; j < 8; ++j) h[j] = (_Float16)W1[(k0 + j) * H + col];
        reinterpret_cast<half8*>(W1p)[g] = h;
    } else {
        pacc[(bid - 32) * 256 + tid] = 0.f;     // 128*256 = 32768 exactly
        if (bid == 32 && tid < BATCH) pz[tid] = 0.f;
    }
}

// ---------------------------------------------------------------------------
// FUSED persistent-pipelined kernel. Block handles TPB=4 consecutive 64-row
// tiles. Pipeline per tile:
//   1. cvt staged regs (tile t) -> XOR-swizzled f16 LDS
//   2. issue tile t+1's 16 global dwordx4 loads (latency hides under 3-5)
//   3. MFMA scores (unroll-2 ks loop) -> tanh -> W2 dot -> exp -> scL
//   4. PV from LDS, accumulating (a4, z) in registers ACROSS tiles per gap;
//      atomic flush only on gap change / block end (gaps avg 16 tiles).
// Max-free softmax (|score| <= ~13). Grid = 512 = 2 blocks/CU, uniform work.
// ---------------------------------------------------------------------------
__global__ __launch_bounds__(256, 2) void fused_kernel(
    const float* __restrict__ X, const _Float16* __restrict__ W1p,
    const float* __restrict__ b1, const float* __restrict__ W2,
    const float* __restrict__ b2, const int* __restrict__ offsets,
    float* __restrict__ pacc, float* __restrict__ pz)
{
    __shared__ __align__(16) _Float16 Xs[64 * H];   // 32 KB, swizzled
    __shared__ float sp[4][64];
    __shared__ float scL[64];
    __shared__ float accL[4][H];
    __shared__ float zLs[4];
    __shared__ int offL[BATCH];

    const int tid = threadIdx.x;
    const int wave = tid >> 6;
    const int lane = tid & 63;

    // XCD-chunked bijective swizzle (512 % 8 == 0): contiguous 64-block
    // chunks per XCD -> gap atomics + X stream stay XCD-local.
    const int bid = (int)(blockIdx.x & 7) * (GRID / 8) + (int)(blockIdx.x >> 3);
    const int tbase = bid * TPB;

    if (tid < BATCH) offL[tid] = offsets[tid];   // visible after first barrier

    const float4* X4 = reinterpret_cast<const float4*>(X);

    // ---- prologue: issue tile tbase's loads into registers ----
    float4 va[8], vb[8];
    {
        const float4* Xv = X4 + (long long)tbase * 64 * 64;
        #pragma unroll
        for (int i = 0; i < 8; ++i) {
            const int c = tid + i * 256;
            const int row = c >> 5;
            const int col8 = c & 31;
            va[i] = Xv[row * 64 + col8 * 2];
            vb[i] = Xv[row * 64 + col8 * 2 + 1];
        }
    }

    float w2v[4], b1v[4];
    #pragma unroll
    for (int ctl = 0; ctl < 4; ++ctl) {
        const int col = wave * 64 + ctl * 16 + (lane & 15);
        w2v[ctl] = W2[col];
        b1v[ctl] = b1[col];
    }
    const float bias2 = b2[0];

    const half8* Bw = reinterpret_cast<const half8*>(W1p) + wave * 2048 + lane;

    float4 a4 = {0.f, 0.f, 0.f, 0.f};   // cross-tile per-gap accumulator
    float zacc = 0.f;
    int g_cur = -1;

    auto flushFn = [&]() {
        reinterpret_cast<float4*>(&accL[wave][0])[lane] = a4;
        if (lane == 0) zLs[wave] = zacc;
        __syncthreads();
        const float v = accL[0][tid] + accL[1][tid] + accL[2][tid] + accL[3][tid];
        atomicAdd(&pacc[g_cur * H + tid], v);
        if (tid == 0) atomicAdd(&pz[g_cur], zLs[0] + zLs[1] + zLs[2] + zLs[3]);
        __syncthreads();   // accL free for reuse
        a4 = (float4){0.f, 0.f, 0.f, 0.f};
        zacc = 0.f;
    };

    for (int t = 0; t < TPB; ++t) {
        const int t0 = (tbase + t) * 64;

        // ---- 1. cvt staged regs -> swizzled LDS (implicit vmcnt wait) ----
        #pragma unroll
        for (int i = 0; i < 8; ++i) {
            const int c = tid + i * 256;
            const int row = c >> 5;
            const int col8 = c & 31;
            half8 h;
            h[0] = (_Float16)va[i].x; h[1] = (_Float16)va[i].y;
            h[2] = (_Float16)va[i].z; h[3] = (_Float16)va[i].w;
            h[4] = (_Float16)vb[i].x; h[5] = (_Float16)vb[i].y;
            h[6] = (_Float16)vb[i].z; h[7] = (_Float16)vb[i].w;
            int byte = row * 512 + col8 * 16;
            byte ^= (row & 7) << 4;
            *reinterpret_cast<half8*>(reinterpret_cast<char*>(Xs) + byte) = h;
        }
        // ---- 2. issue next tile's loads (async; consumed next iter) ----
        if (t < TPB - 1) {
            const float4* Xv = X4 + (long long)(tbase + t + 1) * 64 * 64;
            #pragma unroll
            for (int i = 0; i < 8; ++i) {
                const int c = tid + i * 256;
                const int row = c >> 5;
                const int col8 = c & 31;
                va[i] = Xv[row * 64 + col8 * 2];
                vb[i] = Xv[row * 64 + col8 * 2 + 1];
            }
        }
        __syncthreads();   // Xs ready (t=0: offL also visible)

        // ---- 3. MFMA scores ----
        floatx4 acc[4][4];
        #pragma unroll
        for (int rt = 0; rt < 4; ++rt)
            #pragma unroll
            for (int ctl = 0; ctl < 4; ++ctl)
                acc[rt][ctl] = (floatx4){0.f, 0.f, 0.f, 0.f};

        #pragma unroll 2
        for (int ks = 0; ks < 8; ++ks) {
            half8 bf0 = Bw[ks * 64];
            half8 bf1 = Bw[512 + ks * 64];
            half8 bf2 = Bw[1024 + ks * 64];
            half8 bf3 = Bw[1536 + ks * 64];
            half8 af[4];
            #pragma unroll
            for (int rt = 0; rt < 4; ++rt) {
                const int row = rt * 16 + (lane & 15);
                int byte = row * 512 + ks * 64 + (lane >> 4) * 16;
                byte ^= (row & 7) << 4;
                af[rt] = *reinterpret_cast<const half8*>(
                    reinterpret_cast<const char*>(Xs) + byte);
            }
            #pragma unroll
            for (int rt = 0; rt < 4; ++rt) {
                acc[rt][0] = __builtin_amdgcn_mfma_f32_16x16x32_f16(af[rt], bf0, acc[rt][0], 0, 0, 0);
                acc[rt][1] = __builtin_amdgcn_mfma_f32_16x16x32_f16(af[rt], bf1, acc[rt][1], 0, 0, 0);
                acc[rt][2] = __builtin_amdgcn_mfma_f32_16x16x32_f16(af[rt], bf2, acc[rt][2], 0, 0, 0);
                acc[rt][3] = __builtin_amdgcn_mfma_f32_16x16x32_f16(af[rt], bf3, acc[rt][3], 0, 0, 0);
            }
        }

        // epilogue: tanh + W2 dot -> exp(score) in scL
        float sc[4][4];
        #pragma unroll
        for (int rt = 0; rt < 4; ++rt) {
            #pragma unroll
            for (int reg = 0; reg < 4; ++reg) {
                float s = 0.f;
                #pragma unroll
                for (int ctl = 0; ctl < 4; ++ctl) {
                    const float x = acc[rt][ctl][reg] + b1v[ctl];
                    const float tt = 1.f - 2.f / (__expf(2.f * x) + 1.f);
                    s = fmaf(tt, w2v[ctl], s);
                }
                sc[rt][reg] = s;
            }
        }
        #pragma unroll
        for (int off = 1; off < 16; off <<= 1)
            #pragma unroll
            for (int rt = 0; rt < 4; ++rt)
                #pragma unroll
                for (int reg = 0; reg < 4; ++reg)
                    sc[rt][reg] += __shfl_xor(sc[rt][reg], off);

        if ((lane & 15) == 0) {
            #pragma unroll
            for (int rt = 0; rt < 4; ++rt)
                #pragma unroll
                for (int reg = 0; reg < 4; ++reg)
                    sp[wave][rt * 16 + (lane >> 4) * 4 + reg] = sc[rt][reg];
        }
        __syncthreads();
        if (tid < 64)
            scL[tid] = __expf(sp[0][tid] + sp[1][tid] + sp[2][tid] + sp[3][tid] + bias2);
        __syncthreads();

        // ---- 4. PV from LDS; cross-tile per-gap register accumulation ----
        int g_lo, g_hi;
        {
            int node = t0;
            if (node < offL[0]) g_lo = -1;
            else {
                int lo = 0, hi = BATCH - 1;
                while (lo < hi) { int mid = (lo + hi + 1) >> 1; if (offL[mid] <= node) lo = mid; else hi = mid - 1; }
                g_lo = lo;
            }
            node = t0 + 63;
            if (node < offL[0]) g_hi = -1;
            else {
                int lo = 0, hi = BATCH - 1;
                while (lo < hi) { int mid = (lo + hi + 1) >> 1; if (offL[mid] <= node) lo = mid; else hi = mid - 1; }
                g_hi = lo;
            }
        }

        for (int g = (g_lo < 0 ? 0 : g_lo); g <= g_hi; ++g) {
            if (g != g_cur) {
                if (g_cur >= 0) flushFn();
                g_cur = g;
            }
            const int rs = max(t0, offL[g]);
            const int re = min(t0 + 64, (g == BATCH - 1) ? N_NODES : offL[g + 1]);
            for (int i = rs + wave; i < re; i += 4) {
                const int r = i - t0;
                const float p = scL[r];
                const int byte = r * 512 + ((((lane >> 1) ^ (r & 7))) << 4) + (lane & 1) * 8;
                half4 xv = *reinterpret_cast<const half4*>(
                    reinterpret_cast<const char*>(Xs) + byte);
                a4.x = fmaf(p, (float)xv[0], a4.x);
                a4.y = fmaf(p, (float)xv[1], a4.y);
                a4.z = fmaf(p, (float)xv[2], a4.z);
                a4.w = fmaf(p, (float)xv[3], a4.w);
                zacc += p;
            }
        }
        __syncthreads();   // all PV reads of Xs/scL done before next cvt-write
    }
    if (g_cur >= 0) flushFn();
}

// ---------------------------------------------------------------------------
// Reduce: segment b = union of gaps [max(b-1,0), min(b+1,127)].
// out = sum(acc_g) / sum(z_g). 128 blocks x 256 threads.
// ---------------------------------------------------------------------------
__global__ __launch_bounds__(256) void reduce_kernel(
    const float* __restrict__ pacc, const float* __restrict__ pz,
    float* __restrict__ out)
{
    const int b = blockIdx.x;
    const int tid = threadIdx.x;
    const int g0 = (b == 0) ? 0 : b - 1;
    const int g1 = (b >= BATCH - 1) ? BATCH - 1 : b + 1;

    float r = 0.f, z = 0.f;
    for (int g = g0; g <= g1; ++g) {
        r += pacc[g * H + tid];
        z += pz[g];
    }
    out[b * H + tid] = r / z;
}

// ---------------------------------------------------------------------------
extern "C" void kernel_launch(void* const* d_in, const int* in_sizes, int n_in,
                              void* d_out, int out_size, void* d_ws, size_t ws_size,
                              hipStream_t stream)
{
    const float* X     = (const float*)d_in[0];
    const int* offs    = (const int*)d_in[1];   // int64 in ref -> int32 on device
    const float* W1    = (const float*)d_in[2];
    const float* b1    = (const float*)d_in[3];
    const float* W2    = (const float*)d_in[4];
    const float* b2    = (const float*)d_in[5];
    float* out         = (float*)d_out;

    // workspace layout (floats):
    //   [0, 32768)        pacc   (128 gaps x 256)
    //   [32768, 32896)    pz     (128)
    //   [32896, ...)      W1p    (65536 f16 = 128 KB)
    float* pacc   = (float*)d_ws;
    float* pz     = pacc + BATCH * H;
    _Float16* W1p = (_Float16*)(pz + BATCH);

    prep_kernel<<<160, 256, 0, stream>>>(W1, W1p, pacc, pz);
    fused_kernel<<<GRID, 256, 0, stream>>>(X, W1p, b1, W2, b2, offs, pacc, pz);
    reduce_kernel<<<BATCH, 256, 0, stream>>>(pacc, pz, out);
}